// Round 2
// baseline (197.247 us; speedup 1.0000x reference)
//
#include <hip/hip_runtime.h>

// NGP multiresolution hash-grid interpolation encoding.
// B=262144 points, DIM=3, L=16 levels, T=19 (2^19 entries/level), F=2.
//
// R6: split coarse/fine into separate kernels.
// R5 post-mortem: unified kernel's static 140.6KB LDS capped the fine path
// at 16 waves/CU (Occupancy 71%->30%); L2 request rate fell 12.6->10.5
// req/cyc/XCD, cancelling the -19% request reduction from coarse caching.
//  - ngp_coarse_kernel: levels 0-2 dense LDS sub-table (39/74/141 KB),
//    96 blocks x 1024 thr, ~6us. All L2 gathers for these levels removed.
//  - ngp_fine_kernel: levels 3-15, 256-thr blocks, no LDS (R4 shape,
//    ~20 VGPR, full occupancy), level-major balanced across 8 XCDs:
//    2.55M req/XCD @ 12.6 req/cyc ~ 84us.

#define NB 262144
#define NL 16
#define TSIZE (1u << 19)
#define TMASK ((1u << 19) - 1u)
#define P1 2654435761u
#define P2 805459861u

// coarse (LDS-cached) level config
#define NCL 3                       // levels 0,1,2 cached (extents 17,21,26)
#define LDS_ENT (26 * 26 * 26)      // 17576 entries * 8B = 140608 B
#define CPTS 8192                   // points per coarse block
#define CBLKS (NB / CPTS)           // 32 blocks per coarse level
#define COARSE_BLOCKS (NCL * CBLKS) // 96
// fine config: 13 levels x 1024 chunks of 256 points
#define FINE_CHUNKS 1024
#define FINE_TOTAL ((NL - NCL) * FINE_CHUNKS)  // 13312
#define FINE_PER_XCD (FINE_TOTAL / 8)          // 1664

typedef float vf2 __attribute__((ext_vector_type(2)));
typedef float vf4 __attribute__((ext_vector_type(4)));

__constant__ float RES_C[NL] = {16.f, 20.f, 25.f, 32.f, 40.f, 50.f, 64.f, 80.f,
                                101.f, 128.f, 161.f, 203.f, 256.f, 322.f, 406.f, 512.f};

__device__ __forceinline__ void ngp_point_level(
    float px, float py, float pz, int l, const float* __restrict__ tables,
    float& o0, float& o1) {
  const float res = RES_C[l];
  const float sx = px * res, sy = py * res, sz = pz * res;
  const float fx = floorf(sx), fy = floorf(sy), fz = floorf(sz);
  const unsigned ix = (unsigned)fx, iy = (unsigned)fy, iz = (unsigned)fz;

  const unsigned hy0 = iy * P1, hy1 = hy0 + P1;
  const unsigned hz0 = iz * P2, hz1 = hz0 + P2;

  const float wx0 = 1.0f - fabsf(sx - fx);
  const float wx1 = 1.0f - fabsf(sx - (fx + 1.0f));
  const float wy0 = 1.0f - fabsf(sy - fy);
  const float wy1 = 1.0f - fabsf(sy - (fy + 1.0f));
  const float wz0 = 1.0f - fabsf(sz - fz);
  const float wz1 = 1.0f - fabsf(sz - (fz + 1.0f));

  const vf2* __restrict__ tbl2 = (const vf2*)tables + (size_t)l * TSIZE;
  const vf4* __restrict__ tbl4 = (const vf4*)tables + (size_t)l * (TSIZE / 2);

  unsigned hyz[4];
  hyz[0] = hy0 ^ hz0;
  hyz[1] = hy1 ^ hz0;
  hyz[2] = hy0 ^ hz1;
  hyz[3] = hy1 ^ hz1;

  vf2 g[8];  // g[v], v = xbit + 2*ybit + 4*zbit
  if ((ix & 1u) == 0u) {
    // even ix: x1 corner index = x0 index ^ 1 -> one aligned 16B pair.
#pragma unroll
    for (int p = 0; p < 4; ++p) {
      const unsigned i0 = (ix ^ hyz[p]) & TMASK;
      const vf4 q = tbl4[i0 >> 1];
      vf2 lo; lo.x = q.x; lo.y = q.y;
      vf2 hi; hi.x = q.z; hi.y = q.w;
      const bool x0_is_lo = (i0 & 1u) == 0u;
      g[2 * p + 0] = x0_is_lo ? lo : hi;
      g[2 * p + 1] = x0_is_lo ? hi : lo;
    }
  } else {
#pragma unroll
    for (int p = 0; p < 4; ++p) {
      const unsigned i0 = (ix ^ hyz[p]) & TMASK;
      const unsigned i1 = ((ix + 1u) ^ hyz[p]) & TMASK;
      g[2 * p + 0] = tbl2[i0];
      g[2 * p + 1] = tbl2[i1];
    }
  }

  o0 = 0.0f; o1 = 0.0f;
#pragma unroll
  for (int v = 0; v < 8; ++v) {
    const float w = ((v & 1) ? wx1 : wx0) * ((v & 2) ? wy1 : wy0) * ((v & 4) ? wz1 : wz0);
    o0 = fmaf(w, g[v].x, o0);
    o1 = fmaf(w, g[v].y, o1);
  }
}

// ---- coarse level: dense LDS sub-table fill + LDS trilinear ----
template <int E>
__device__ __forceinline__ void coarse_block(
    const int lvl, const int cchunk, const float* __restrict__ x,
    const float* __restrict__ tables, vf2* __restrict__ ws,
    vf2* __restrict__ cache) {
  const int tid = threadIdx.x;
  const vf4* __restrict__ tbl4 = (const vf4*)tables + (size_t)lvl * (TSIZE / 2);

  constexpr int HE = (E + 1) / 2;   // x-pairs per row
  constexpr int U = HE * E * E;     // fill units

  // Fill: iterate even-x pairs of the dense coord grid; hash -> one aligned
  // 16B load serves both x corners. Footprint 39-141KB, L2-resident across
  // the 32 blocks of a level.
  for (int u = tid; u < U; u += 1024) {
    const int iz = u / (HE * E);
    const int rem = u - iz * (HE * E);
    const int iy = rem / HE;
    const int ixh = rem - iy * HE;
    const unsigned ix = 2u * (unsigned)ixh;
    const unsigned h0 = (ix ^ ((unsigned)iy * P1) ^ ((unsigned)iz * P2)) & TMASK;
    const vf4 q = tbl4[h0 >> 1];
    vf2 lo; lo.x = q.x; lo.y = q.y;
    vf2 hi; hi.x = q.z; hi.y = q.w;
    const bool x0_is_lo = (h0 & 1u) == 0u;
    const int d0 = (int)ix + E * (iy + E * iz);
    cache[d0] = x0_is_lo ? lo : hi;
    if ((int)ix + 1 < E) cache[d0 + 1] = x0_is_lo ? hi : lo;
  }
  __syncthreads();

  const float res = RES_C[lvl];
  const int base = cchunk * CPTS;
#pragma unroll
  for (int k = 0; k < CPTS / 1024; ++k) {
    const int b = base + k * 1024 + tid;
    const float px = __builtin_nontemporal_load(x + b * 3 + 0);
    const float py = __builtin_nontemporal_load(x + b * 3 + 1);
    const float pz = __builtin_nontemporal_load(x + b * 3 + 2);

    const float sx = px * res, sy = py * res, sz = pz * res;
    const float fx = floorf(sx), fy = floorf(sy), fz = floorf(sz);
    const int ix = (int)fx, iy = (int)fy, iz = (int)fz;

    const float wx0 = 1.0f - fabsf(sx - fx);
    const float wx1 = 1.0f - fabsf(sx - (fx + 1.0f));
    const float wy0 = 1.0f - fabsf(sy - fy);
    const float wy1 = 1.0f - fabsf(sy - (fy + 1.0f));
    const float wz0 = 1.0f - fabsf(sz - fz);
    const float wz1 = 1.0f - fabsf(sz - (fz + 1.0f));

    const int d = ix + E * (iy + E * iz);
    vf2 g[8];
    g[0] = cache[d];
    g[1] = cache[d + 1];
    g[2] = cache[d + E];
    g[3] = cache[d + E + 1];
    g[4] = cache[d + E * E];
    g[5] = cache[d + E * E + 1];
    g[6] = cache[d + E * E + E];
    g[7] = cache[d + E * E + E + 1];

    float o0 = 0.0f, o1 = 0.0f;
#pragma unroll
    for (int v = 0; v < 8; ++v) {
      const float w = ((v & 1) ? wx1 : wx0) * ((v & 2) ? wy1 : wy0) * ((v & 4) ? wz1 : wz0);
      o0 = fmaf(w, g[v].x, o0);
      o1 = fmaf(w, g[v].y, o1);
    }
    vf2 r; r.x = o0; r.y = o1;
    __builtin_nontemporal_store(r, ws + (size_t)lvl * NB + b);
  }
}

// ---- phase 1a: coarse levels 0-2 via LDS dense cache ----
__global__ __launch_bounds__(1024) void ngp_coarse_kernel(
    const float* __restrict__ x, const float* __restrict__ tables,
    vf2* __restrict__ ws) {
  __shared__ vf2 cache[LDS_ENT];
  const int u = blockIdx.x;            // 0..95
  const int lvl = u >> 5;              // 0..2
  const int cchunk = u & 31;
  switch (lvl) {
    case 0: coarse_block<17>(0, cchunk, x, tables, ws, cache); break;
    case 1: coarse_block<21>(1, cchunk, x, tables, ws, cache); break;
    default: coarse_block<26>(2, cchunk, x, tables, ws, cache); break;
  }
}

// ---- phase 1b: fine levels 3-15, no LDS, full occupancy ----
// bid%8 = XCD (dispatch round-robin). Each XCD walks its 1664 chunks in
// level-major order, so its L2 holds ~one 4MB table at a time.
__global__ __launch_bounds__(256) void ngp_fine_kernel(
    const float* __restrict__ x,       // (B, 3)
    const float* __restrict__ tables,  // (L, 2^19, 2)
    vf2* __restrict__ ws) {            // (L, B)
  const int x8 = blockIdx.x & 7;
  const int j = blockIdx.x >> 3;                 // 0..1663
  const int g = x8 * FINE_PER_XCD + j;           // 0..13311
  const int lvl = NCL + (g >> 10);               // 3..15
  const int b = (g & 1023) * 256 + threadIdx.x;

  const float px = __builtin_nontemporal_load(x + b * 3 + 0);
  const float py = __builtin_nontemporal_load(x + b * 3 + 1);
  const float pz = __builtin_nontemporal_load(x + b * 3 + 2);

  float o0, o1;
  ngp_point_level(px, py, pz, lvl, tables, o0, o1);

  vf2 r; r.x = o0; r.y = o1;
  __builtin_nontemporal_store(r, ws + (size_t)lvl * NB + b);
}

// ---- phase 2: transpose ws[l][b] -> out[b][l*2+f], streaming ----
__global__ __launch_bounds__(256) void ngp_transpose_kernel(
    const vf2* __restrict__ ws,  // (L, B)
    vf4* __restrict__ out4) {    // (B, 8) float4 view of (B, 32) floats
  __shared__ vf2 tile[NL][257];
  const int t = threadIdx.x;
  const int p0 = blockIdx.x * 256;

#pragma unroll
  for (int l = 0; l < NL; ++l) {
    tile[l][t] = __builtin_nontemporal_load(ws + (size_t)l * NB + p0 + t);
  }
  __syncthreads();

#pragma unroll
  for (int k = 0; k < 8; ++k) {
    const int q = k * 256 + t;
    const int pq = q >> 3;
    const int wq = q & 7;
    const vf2 a = tile[2 * wq + 0][pq];
    const vf2 c = tile[2 * wq + 1][pq];
    vf4 v; v.x = a.x; v.y = a.y; v.z = c.x; v.w = c.y;
    __builtin_nontemporal_store(v, out4 + (size_t)p0 * 8 + q);
  }
}

// ---- fallback if workspace too small ----
__global__ __launch_bounds__(256) void ngp_fused_kernel(
    const float* __restrict__ x, const float* __restrict__ tables,
    float* __restrict__ out) {
  const int tid = blockIdx.x * blockDim.x + threadIdx.x;
  const int l = tid & (NL - 1);
  const int b = tid >> 4;
  float o0, o1;
  ngp_point_level(x[b * 3], x[b * 3 + 1], x[b * 3 + 2], l, tables, o0, o1);
  float2 r = make_float2(o0, o1);
  ((float2*)out)[tid] = r;
}

extern "C" void kernel_launch(void* const* d_in, const int* in_sizes, int n_in,
                              void* d_out, int out_size, void* d_ws, size_t ws_size,
                              hipStream_t stream) {
  const float* x = (const float*)d_in[0];
  const float* tables = (const float*)d_in[1];
  float* out = (float*)d_out;

  const size_t ws_needed = (size_t)NL * NB * sizeof(vf2);  // 32 MB
  if (ws_size >= ws_needed) {
    vf2* ws = (vf2*)d_ws;
    ngp_coarse_kernel<<<COARSE_BLOCKS, 1024, 0, stream>>>(x, tables, ws);
    ngp_fine_kernel<<<FINE_TOTAL, 256, 0, stream>>>(x, tables, ws);
    ngp_transpose_kernel<<<NB / 256, 256, 0, stream>>>(ws, (vf4*)out);
  } else {
    ngp_fused_kernel<<<NB * NL / 256, 256, 0, stream>>>(x, tables, out);
  }
}

// Round 3
// 190.833 us; speedup vs baseline: 1.0336x; 1.0336x over previous
//
#include <hip/hip_runtime.h>

// NGP multiresolution hash-grid interpolation encoding.
// B=262144 points, DIM=3, L=16 levels, T=19 (2^19 entries/level), F=2.
//
// R7: unified gather, 2 blocks/CU.
// R6 post-mortem: separate coarse kernel's dispatch boundary (+~7us) plus
// serialization (+~8us) outweighed the fine-path occupancy win; same-stream
// kernels never overlap. R5 post-mortem: 140.6KB static LDS in a unified
// kernel taxed fine blocks to 1 block/CU.
// Fix: unified kernel with LDS <= 75.7KB so TWO 1024-thr blocks co-reside
// per CU (32 waves, full occupancy for the fine path):
//  - level 0 (17^3=39KB) and level 1 (21^3=74KB) cached whole;
//  - level 2 (26^3=141KB) split into two z-halves of 26x26x14=75.7KB,
//    each chunk visited by two exec-masked half-blocks;
//  - 128 coarse blocks dispatched first (16/XCD), hidden under the
//    3328-block fine flood (levels 3-15, XCD-pinned level-major).

#define NB 262144
#define NL 16
#define TSIZE (1u << 19)
#define TMASK ((1u << 19) - 1u)
#define P1 2654435761u
#define P2 805459861u

#define NCL 3
#define CPTS 8192                      // points per coarse block
#define CBLKS (NB / CPTS)              // 32 chunks per coarse level
#define COARSE_BLOCKS 128              // 32 (L0) + 32 (L1) + 64 (L2 halves)
#define CLDS_ENT (26 * 26 * 14)        // 9464 entries * 8B = 75712 B
// fine: 13 levels x 256 chunks of 1024 points
#define FINE_CHUNKS 256
#define FINE_TOTAL ((NL - NCL) * FINE_CHUNKS)  // 3328
#define FINE_PER_XCD (FINE_TOTAL / 8)          // 416
#define GRID_BLOCKS (COARSE_BLOCKS + FINE_TOTAL)  // 3456

typedef float vf2 __attribute__((ext_vector_type(2)));
typedef float vf4 __attribute__((ext_vector_type(4)));

__constant__ float RES_C[NL] = {16.f, 20.f, 25.f, 32.f, 40.f, 50.f, 64.f, 80.f,
                                101.f, 128.f, 161.f, 203.f, 256.f, 322.f, 406.f, 512.f};

__device__ __forceinline__ void ngp_point_level(
    float px, float py, float pz, int l, const float* __restrict__ tables,
    float& o0, float& o1) {
  const float res = RES_C[l];
  const float sx = px * res, sy = py * res, sz = pz * res;
  const float fx = floorf(sx), fy = floorf(sy), fz = floorf(sz);
  const unsigned ix = (unsigned)fx, iy = (unsigned)fy, iz = (unsigned)fz;

  const unsigned hy0 = iy * P1, hy1 = hy0 + P1;
  const unsigned hz0 = iz * P2, hz1 = hz0 + P2;

  const float wx0 = 1.0f - fabsf(sx - fx);
  const float wx1 = 1.0f - fabsf(sx - (fx + 1.0f));
  const float wy0 = 1.0f - fabsf(sy - fy);
  const float wy1 = 1.0f - fabsf(sy - (fy + 1.0f));
  const float wz0 = 1.0f - fabsf(sz - fz);
  const float wz1 = 1.0f - fabsf(sz - (fz + 1.0f));

  const vf2* __restrict__ tbl2 = (const vf2*)tables + (size_t)l * TSIZE;
  const vf4* __restrict__ tbl4 = (const vf4*)tables + (size_t)l * (TSIZE / 2);

  unsigned hyz[4];
  hyz[0] = hy0 ^ hz0;
  hyz[1] = hy1 ^ hz0;
  hyz[2] = hy0 ^ hz1;
  hyz[3] = hy1 ^ hz1;

  vf2 g[8];  // g[v], v = xbit + 2*ybit + 4*zbit
  if ((ix & 1u) == 0u) {
    // even ix: x1 corner index = x0 index ^ 1 -> one aligned 16B pair.
#pragma unroll
    for (int p = 0; p < 4; ++p) {
      const unsigned i0 = (ix ^ hyz[p]) & TMASK;
      const vf4 q = tbl4[i0 >> 1];
      vf2 lo; lo.x = q.x; lo.y = q.y;
      vf2 hi; hi.x = q.z; hi.y = q.w;
      const bool x0_is_lo = (i0 & 1u) == 0u;
      g[2 * p + 0] = x0_is_lo ? lo : hi;
      g[2 * p + 1] = x0_is_lo ? hi : lo;
    }
  } else {
#pragma unroll
    for (int p = 0; p < 4; ++p) {
      const unsigned i0 = (ix ^ hyz[p]) & TMASK;
      const unsigned i1 = ((ix + 1u) ^ hyz[p]) & TMASK;
      g[2 * p + 0] = tbl2[i0];
      g[2 * p + 1] = tbl2[i1];
    }
  }

  o0 = 0.0f; o1 = 0.0f;
#pragma unroll
  for (int v = 0; v < 8; ++v) {
    const float w = ((v & 1) ? wx1 : wx0) * ((v & 2) ? wy1 : wy0) * ((v & 4) ? wz1 : wz0);
    o0 = fmaf(w, g[v].x, o0);
    o1 = fmaf(w, g[v].y, o1);
  }
}

// ---- coarse full-level block (levels 0,1): dense LDS sub-table ----
template <int E>
__device__ __forceinline__ void coarse_full(
    const int lvl, const int cchunk, const float* __restrict__ x,
    const float* __restrict__ tables, vf2* __restrict__ ws,
    vf2* __restrict__ cache) {
  const int tid = threadIdx.x;
  const vf4* __restrict__ tbl4 = (const vf4*)tables + (size_t)lvl * (TSIZE / 2);

  constexpr int HE = (E + 1) / 2;   // x-pairs per row
  constexpr int U = HE * E * E;

  for (int u = tid; u < U; u += 1024) {
    const int iz = u / (HE * E);
    const int rem = u - iz * (HE * E);
    const int iy = rem / HE;
    const int ixh = rem - iy * HE;
    const unsigned ix = 2u * (unsigned)ixh;
    const unsigned h0 = (ix ^ ((unsigned)iy * P1) ^ ((unsigned)iz * P2)) & TMASK;
    const vf4 q = tbl4[h0 >> 1];
    vf2 lo; lo.x = q.x; lo.y = q.y;
    vf2 hi; hi.x = q.z; hi.y = q.w;
    const bool x0_is_lo = (h0 & 1u) == 0u;
    const int d0 = (int)ix + E * (iy + E * iz);
    cache[d0] = x0_is_lo ? lo : hi;
    if ((int)ix + 1 < E) cache[d0 + 1] = x0_is_lo ? hi : lo;
  }
  __syncthreads();

  const float res = RES_C[lvl];
  const int base = cchunk * CPTS;
#pragma unroll
  for (int k = 0; k < CPTS / 1024; ++k) {
    const int b = base + k * 1024 + tid;
    const float px = __builtin_nontemporal_load(x + b * 3 + 0);
    const float py = __builtin_nontemporal_load(x + b * 3 + 1);
    const float pz = __builtin_nontemporal_load(x + b * 3 + 2);

    const float sx = px * res, sy = py * res, sz = pz * res;
    const float fx = floorf(sx), fy = floorf(sy), fz = floorf(sz);
    const int ix = (int)fx, iy = (int)fy, iz = (int)fz;

    const float wx0 = 1.0f - fabsf(sx - fx);
    const float wx1 = 1.0f - fabsf(sx - (fx + 1.0f));
    const float wy0 = 1.0f - fabsf(sy - fy);
    const float wy1 = 1.0f - fabsf(sy - (fy + 1.0f));
    const float wz0 = 1.0f - fabsf(sz - fz);
    const float wz1 = 1.0f - fabsf(sz - (fz + 1.0f));

    const int d = ix + E * (iy + E * iz);
    vf2 g[8];
    g[0] = cache[d];
    g[1] = cache[d + 1];
    g[2] = cache[d + E];
    g[3] = cache[d + E + 1];
    g[4] = cache[d + E * E];
    g[5] = cache[d + E * E + 1];
    g[6] = cache[d + E * E + E];
    g[7] = cache[d + E * E + E + 1];

    float o0 = 0.0f, o1 = 0.0f;
#pragma unroll
    for (int v = 0; v < 8; ++v) {
      const float w = ((v & 1) ? wx1 : wx0) * ((v & 2) ? wy1 : wy0) * ((v & 4) ? wz1 : wz0);
      o0 = fmaf(w, g[v].x, o0);
      o1 = fmaf(w, g[v].y, o1);
    }
    vf2 r; r.x = o0; r.y = o1;
    __builtin_nontemporal_store(r, ws + (size_t)lvl * NB + b);
  }
}

// ---- coarse level-2 half block: z-slab [zb, zb+planes-1] of the 26^3 grid ----
__device__ __forceinline__ void coarse_half_l2(
    const int half, const int cchunk, const float* __restrict__ x,
    const float* __restrict__ tables, vf2* __restrict__ ws,
    vf2* __restrict__ cache) {
  const int tid = threadIdx.x;
  const vf4* __restrict__ tbl4 = (const vf4*)tables + (size_t)2 * (TSIZE / 2);

  const int zb = half ? 13 : 0;
  const int planes = half ? 13 : 14;     // corner z range: [0,13] / [13,25]
  const int U = 13 * 26 * planes;        // HE=13, E=26

  for (int u = tid; u < U; u += 1024) {
    const int zp = u / (13 * 26);
    const int rem = u - zp * (13 * 26);
    const int iy = rem / 13;
    const int ixh = rem - iy * 13;
    const unsigned ix = 2u * (unsigned)ixh;
    const unsigned iz = (unsigned)(zb + zp);
    const unsigned h0 = (ix ^ ((unsigned)iy * P1) ^ (iz * P2)) & TMASK;
    const vf4 q = tbl4[h0 >> 1];
    vf2 lo; lo.x = q.x; lo.y = q.y;
    vf2 hi; hi.x = q.z; hi.y = q.w;
    const bool x0_is_lo = (h0 & 1u) == 0u;
    const int d0 = (int)ix + 26 * iy + 676 * zp;
    cache[d0] = x0_is_lo ? lo : hi;
    if ((int)ix + 1 < 26) cache[d0 + 1] = x0_is_lo ? hi : lo;
  }
  __syncthreads();

  const float res = RES_C[2];  // 25
  const int base = cchunk * CPTS;
#pragma unroll
  for (int k = 0; k < CPTS / 1024; ++k) {
    const int b = base + k * 1024 + tid;
    const float px = __builtin_nontemporal_load(x + b * 3 + 0);
    const float py = __builtin_nontemporal_load(x + b * 3 + 1);
    const float pz = __builtin_nontemporal_load(x + b * 3 + 2);

    const float sx = px * res, sy = py * res, sz = pz * res;
    const float fx = floorf(sx), fy = floorf(sy), fz = floorf(sz);
    const int ix = (int)fx, iy = (int)fy, iz = (int)fz;

    // half 0 owns iz<=12, half 1 owns iz>=13; each point handled exactly once
    const bool active = half ? (iz >= 13) : (iz <= 12);
    if (active) {
      const float wx0 = 1.0f - fabsf(sx - fx);
      const float wx1 = 1.0f - fabsf(sx - (fx + 1.0f));
      const float wy0 = 1.0f - fabsf(sy - fy);
      const float wy1 = 1.0f - fabsf(sy - (fy + 1.0f));
      const float wz0 = 1.0f - fabsf(sz - fz);
      const float wz1 = 1.0f - fabsf(sz - (fz + 1.0f));

      const int d = ix + 26 * iy + 676 * (iz - zb);
      vf2 g[8];
      g[0] = cache[d];
      g[1] = cache[d + 1];
      g[2] = cache[d + 26];
      g[3] = cache[d + 27];
      g[4] = cache[d + 676];
      g[5] = cache[d + 677];
      g[6] = cache[d + 702];
      g[7] = cache[d + 703];

      float o0 = 0.0f, o1 = 0.0f;
#pragma unroll
      for (int v = 0; v < 8; ++v) {
        const float w = ((v & 1) ? wx1 : wx0) * ((v & 2) ? wy1 : wy0) * ((v & 4) ? wz1 : wz0);
        o0 = fmaf(w, g[v].x, o0);
        o1 = fmaf(w, g[v].y, o1);
      }
      vf2 r; r.x = o0; r.y = o1;
      __builtin_nontemporal_store(r, ws + (size_t)2 * NB + b);
    }
  }
}

// ---- phase 1: unified gather (coarse-LDS + fine), 2 blocks/CU ----
// bids 0..127: coarse (16/XCD, dispatched first, hidden under fine flood).
// bids 128..3455: fine levels 3-15, XCD-pinned level-major.
__global__ __launch_bounds__(1024, 8) void ngp_gather2(
    const float* __restrict__ x,       // (B, 3)
    const float* __restrict__ tables,  // (L, 2^19, 2)
    vf2* __restrict__ ws) {            // (L, B)
  __shared__ vf2 cache[CLDS_ENT];      // 75712 B -> 2 blocks/CU

  const int bid = blockIdx.x;
  if (bid < COARSE_BLOCKS) {
    if (bid < 32) {
      coarse_full<17>(0, bid & 31, x, tables, ws, cache);
    } else if (bid < 64) {
      coarse_full<21>(1, bid & 31, x, tables, ws, cache);
    } else {
      const int u = bid - 64;          // 0..63
      coarse_half_l2(u >> 5, u & 31, x, tables, ws, cache);
    }
    return;
  }

  const int fid = bid - COARSE_BLOCKS;           // 0..3327
  const int x8 = fid & 7;
  const int j = fid >> 3;                        // 0..415
  const int g = x8 * FINE_PER_XCD + j;           // 0..3327
  const int lvl = NCL + (g >> 8);                // 3..15
  const int b = (g & 255) * 1024 + threadIdx.x;

  const float px = __builtin_nontemporal_load(x + b * 3 + 0);
  const float py = __builtin_nontemporal_load(x + b * 3 + 1);
  const float pz = __builtin_nontemporal_load(x + b * 3 + 2);

  float o0, o1;
  ngp_point_level(px, py, pz, lvl, tables, o0, o1);

  vf2 r; r.x = o0; r.y = o1;
  __builtin_nontemporal_store(r, ws + (size_t)lvl * NB + b);
}

// ---- phase 2: transpose ws[l][b] -> out[b][l*2+f], streaming ----
__global__ __launch_bounds__(256) void ngp_transpose_kernel(
    const vf2* __restrict__ ws,  // (L, B)
    vf4* __restrict__ out4) {    // (B, 8) float4 view of (B, 32) floats
  __shared__ vf2 tile[NL][257];
  const int t = threadIdx.x;
  const int p0 = blockIdx.x * 256;

#pragma unroll
  for (int l = 0; l < NL; ++l) {
    tile[l][t] = __builtin_nontemporal_load(ws + (size_t)l * NB + p0 + t);
  }
  __syncthreads();

#pragma unroll
  for (int k = 0; k < 8; ++k) {
    const int q = k * 256 + t;
    const int pq = q >> 3;
    const int wq = q & 7;
    const vf2 a = tile[2 * wq + 0][pq];
    const vf2 c = tile[2 * wq + 1][pq];
    vf4 v; v.x = a.x; v.y = a.y; v.z = c.x; v.w = c.y;
    __builtin_nontemporal_store(v, out4 + (size_t)p0 * 8 + q);
  }
}

// ---- fallback if workspace too small ----
__global__ __launch_bounds__(256) void ngp_fused_kernel(
    const float* __restrict__ x, const float* __restrict__ tables,
    float* __restrict__ out) {
  const int tid = blockIdx.x * blockDim.x + threadIdx.x;
  const int l = tid & (NL - 1);
  const int b = tid >> 4;
  float o0, o1;
  ngp_point_level(x[b * 3], x[b * 3 + 1], x[b * 3 + 2], l, tables, o0, o1);
  float2 r = make_float2(o0, o1);
  ((float2*)out)[tid] = r;
}

extern "C" void kernel_launch(void* const* d_in, const int* in_sizes, int n_in,
                              void* d_out, int out_size, void* d_ws, size_t ws_size,
                              hipStream_t stream) {
  const float* x = (const float*)d_in[0];
  const float* tables = (const float*)d_in[1];
  float* out = (float*)d_out;

  const size_t ws_needed = (size_t)NL * NB * sizeof(vf2);  // 32 MB
  if (ws_size >= ws_needed) {
    vf2* ws = (vf2*)d_ws;
    ngp_gather2<<<GRID_BLOCKS, 1024, 0, stream>>>(x, tables, ws);
    ngp_transpose_kernel<<<NB / 256, 256, 0, stream>>>(ws, (vf4*)out);
  } else {
    ngp_fused_kernel<<<NB * NL / 256, 256, 0, stream>>>(x, tables, out);
  }
}

// Round 4
// 190.238 us; speedup vs baseline: 1.0368x; 1.0031x over previous
//
#include <hip/hip_runtime.h>

// NGP multiresolution hash-grid interpolation encoding.
// B=262144 points, DIM=3, L=16 levels, T=19 (2^19 entries/level), F=2.
//
// R8: small-slab coarse LDS, 4 blocks/CU.
// R7 post-mortem: 75.7KB LDS blocks failed to pair on a CU (occupancy 54%
// not ~100%); >64KB workgroup LDS effectively serializes workgroups/CU ->
// fine path paid ~6.6us. R6: separate coarse kernel = ~13us serialized.
// Fix: uniform static LDS = 39.3KB (level-0 grid), 512-thr blocks ->
// 4 blocks/CU (157KB LDS, 2048 thr) so the fine path keeps full residency.
// Coarse levels as z-slabs, each slab-block scans its 8192-pt chunk and
// serves only points in its z-range:
//   L0: whole 17^3 grid (39.3KB), 32 blocks
//   L1: 2 z-halves 21x21x11 (38.8KB), 64 blocks
//   L2: 5 z-slabs 26x26x6 (32.4KB), 160 blocks
// 256 coarse blocks first (32/XCD), hidden under 6656 fine blocks
// (13 levels x 512-pt chunks, XCD-pinned level-major as R6).

#define NB 262144
#define NL 16
#define TSIZE (1u << 19)
#define TMASK ((1u << 19) - 1u)
#define P1 2654435761u
#define P2 805459861u

#define NCL 3
#define CPTS 8192                      // points per coarse chunk
#define COARSE_BLOCKS 256              // 32 (L0) + 64 (L1) + 160 (L2)
#define CLDS_ENT (17 * 17 * 17)        // 4913 entries * 8B = 39304 B (max slab)
// fine: 13 levels x 512 chunks of 512 points
#define FINE_CHUNKS 512
#define FINE_TOTAL ((NL - NCL) * FINE_CHUNKS)  // 6656
#define FINE_PER_XCD (FINE_TOTAL / 8)          // 832
#define GRID_BLOCKS (COARSE_BLOCKS + FINE_TOTAL)  // 6912

typedef float vf2 __attribute__((ext_vector_type(2)));
typedef float vf4 __attribute__((ext_vector_type(4)));

__constant__ float RES_C[NL] = {16.f, 20.f, 25.f, 32.f, 40.f, 50.f, 64.f, 80.f,
                                101.f, 128.f, 161.f, 203.f, 256.f, 322.f, 406.f, 512.f};

__device__ __forceinline__ void ngp_point_level(
    float px, float py, float pz, int l, const float* __restrict__ tables,
    float& o0, float& o1) {
  const float res = RES_C[l];
  const float sx = px * res, sy = py * res, sz = pz * res;
  const float fx = floorf(sx), fy = floorf(sy), fz = floorf(sz);
  const unsigned ix = (unsigned)fx, iy = (unsigned)fy, iz = (unsigned)fz;

  const unsigned hy0 = iy * P1, hy1 = hy0 + P1;
  const unsigned hz0 = iz * P2, hz1 = hz0 + P2;

  const float wx0 = 1.0f - fabsf(sx - fx);
  const float wx1 = 1.0f - fabsf(sx - (fx + 1.0f));
  const float wy0 = 1.0f - fabsf(sy - fy);
  const float wy1 = 1.0f - fabsf(sy - (fy + 1.0f));
  const float wz0 = 1.0f - fabsf(sz - fz);
  const float wz1 = 1.0f - fabsf(sz - (fz + 1.0f));

  const vf2* __restrict__ tbl2 = (const vf2*)tables + (size_t)l * TSIZE;
  const vf4* __restrict__ tbl4 = (const vf4*)tables + (size_t)l * (TSIZE / 2);

  unsigned hyz[4];
  hyz[0] = hy0 ^ hz0;
  hyz[1] = hy1 ^ hz0;
  hyz[2] = hy0 ^ hz1;
  hyz[3] = hy1 ^ hz1;

  vf2 g[8];  // g[v], v = xbit + 2*ybit + 4*zbit
  if ((ix & 1u) == 0u) {
    // even ix: x1 corner index = x0 index ^ 1 -> one aligned 16B pair.
#pragma unroll
    for (int p = 0; p < 4; ++p) {
      const unsigned i0 = (ix ^ hyz[p]) & TMASK;
      const vf4 q = tbl4[i0 >> 1];
      vf2 lo; lo.x = q.x; lo.y = q.y;
      vf2 hi; hi.x = q.z; hi.y = q.w;
      const bool x0_is_lo = (i0 & 1u) == 0u;
      g[2 * p + 0] = x0_is_lo ? lo : hi;
      g[2 * p + 1] = x0_is_lo ? hi : lo;
    }
  } else {
#pragma unroll
    for (int p = 0; p < 4; ++p) {
      const unsigned i0 = (ix ^ hyz[p]) & TMASK;
      const unsigned i1 = ((ix + 1u) ^ hyz[p]) & TMASK;
      g[2 * p + 0] = tbl2[i0];
      g[2 * p + 1] = tbl2[i1];
    }
  }

  o0 = 0.0f; o1 = 0.0f;
#pragma unroll
  for (int v = 0; v < 8; ++v) {
    const float w = ((v & 1) ? wx1 : wx0) * ((v & 2) ? wy1 : wy0) * ((v & 4) ? wz1 : wz0);
    o0 = fmaf(w, g[v].x, o0);
    o1 = fmaf(w, g[v].y, o1);
  }
}

// ---- coarse z-slab block: fill LDS with planes [zbase, zbase+PLANES-1] of
// level lvl's dense grid, then serve chunk points with iz in [c_lo, c_hi] ----
template <int E, int PLANES>
__device__ __forceinline__ void coarse_slab(
    const int lvl, const int zbase, const int c_lo, const int c_hi,
    const int cchunk, const float* __restrict__ x,
    const float* __restrict__ tables, vf2* __restrict__ ws,
    vf2* __restrict__ cache) {
  const int tid = threadIdx.x;
  const vf4* __restrict__ tbl4 = (const vf4*)tables + (size_t)lvl * (TSIZE / 2);

  constexpr int HE = (E + 1) / 2;   // even-x pairs per row
  constexpr int U = HE * E * PLANES;

  for (int u = tid; u < U; u += 512) {
    const int zp = u / (HE * E);
    const int rem = u - zp * (HE * E);
    const int iy = rem / HE;
    const int ixh = rem - iy * HE;
    const unsigned ix = 2u * (unsigned)ixh;
    const unsigned iz = (unsigned)(zbase + zp);
    const unsigned h0 = (ix ^ ((unsigned)iy * P1) ^ (iz * P2)) & TMASK;
    const vf4 q = tbl4[h0 >> 1];
    vf2 lo; lo.x = q.x; lo.y = q.y;
    vf2 hi; hi.x = q.z; hi.y = q.w;
    const bool x0_is_lo = (h0 & 1u) == 0u;
    const int d0 = (int)ix + E * iy + E * E * zp;
    cache[d0] = x0_is_lo ? lo : hi;
    if ((int)ix + 1 < E) cache[d0 + 1] = x0_is_lo ? hi : lo;
  }
  __syncthreads();

  const float res = RES_C[lvl];
  const int base = cchunk * CPTS;
#pragma unroll
  for (int k = 0; k < CPTS / 512; ++k) {
    const int b = base + k * 512 + tid;
    const float px = x[b * 3 + 0];
    const float py = x[b * 3 + 1];
    const float pz = x[b * 3 + 2];

    const float sx = px * res, sy = py * res, sz = pz * res;
    const float fx = floorf(sx), fy = floorf(sy), fz = floorf(sz);
    const int ix = (int)fx, iy = (int)fy, iz = (int)fz;

    if (iz >= c_lo && iz <= c_hi) {
      const float wx0 = 1.0f - fabsf(sx - fx);
      const float wx1 = 1.0f - fabsf(sx - (fx + 1.0f));
      const float wy0 = 1.0f - fabsf(sy - fy);
      const float wy1 = 1.0f - fabsf(sy - (fy + 1.0f));
      const float wz0 = 1.0f - fabsf(sz - fz);
      const float wz1 = 1.0f - fabsf(sz - (fz + 1.0f));

      const int d = ix + E * iy + E * E * (iz - zbase);
      vf2 g[8];
      g[0] = cache[d];
      g[1] = cache[d + 1];
      g[2] = cache[d + E];
      g[3] = cache[d + E + 1];
      g[4] = cache[d + E * E];
      g[5] = cache[d + E * E + 1];
      g[6] = cache[d + E * E + E];
      g[7] = cache[d + E * E + E + 1];

      float o0 = 0.0f, o1 = 0.0f;
#pragma unroll
      for (int v = 0; v < 8; ++v) {
        const float w = ((v & 1) ? wx1 : wx0) * ((v & 2) ? wy1 : wy0) * ((v & 4) ? wz1 : wz0);
        o0 = fmaf(w, g[v].x, o0);
        o1 = fmaf(w, g[v].y, o1);
      }
      vf2 r; r.x = o0; r.y = o1;
      __builtin_nontemporal_store(r, ws + (size_t)lvl * NB + b);
    }
  }
}

// ---- phase 1: unified gather (slab-coarse + fine), 4 blocks/CU ----
// bids 0..255: coarse slabs (32/XCD, dispatched first, hidden under fine).
// bids 256..6911: fine levels 3-15, XCD-pinned level-major.
__global__ __launch_bounds__(512, 8) void ngp_gather3(
    const float* __restrict__ x,       // (B, 3)
    const float* __restrict__ tables,  // (L, 2^19, 2)
    vf2* __restrict__ ws) {            // (L, B)
  __shared__ vf2 cache[CLDS_ENT];      // 39304 B -> 4 blocks/CU

  const int bid = blockIdx.x;
  if (bid < COARSE_BLOCKS) {
    if (bid < 32) {
      // level 0: whole 17^3 grid, cells 0..15
      coarse_slab<17, 17>(0, 0, 0, 15, bid, x, tables, ws, cache);
    } else if (bid < 96) {
      // level 1: z-halves of 21^3 grid, cells 0..9 / 10..19
      const int u = bid - 32;
      const int half = u >> 5;
      coarse_slab<21, 11>(1, half * 10, half * 10, half * 10 + 9, u & 31,
                          x, tables, ws, cache);
    } else {
      // level 2: 5 z-slabs of 26^3 grid, cells 5s..5s+4
      const int u = bid - 96;
      const int s = u >> 5;
      coarse_slab<26, 6>(2, 5 * s, 5 * s, 5 * s + 4, u & 31,
                         x, tables, ws, cache);
    }
    return;
  }

  const int fid = bid - COARSE_BLOCKS;           // 0..6655
  const int x8 = fid & 7;
  const int j = fid >> 3;                        // 0..831
  const int g = x8 * FINE_PER_XCD + j;           // 0..6655
  const int lvl = NCL + (g >> 9);                // 3..15
  const int b = (g & 511) * 512 + threadIdx.x;

  const float px = __builtin_nontemporal_load(x + b * 3 + 0);
  const float py = __builtin_nontemporal_load(x + b * 3 + 1);
  const float pz = __builtin_nontemporal_load(x + b * 3 + 2);

  float o0, o1;
  ngp_point_level(px, py, pz, lvl, tables, o0, o1);

  vf2 r; r.x = o0; r.y = o1;
  __builtin_nontemporal_store(r, ws + (size_t)lvl * NB + b);
}

// ---- phase 2: transpose ws[l][b] -> out[b][l*2+f], streaming ----
__global__ __launch_bounds__(256) void ngp_transpose_kernel(
    const vf2* __restrict__ ws,  // (L, B)
    vf4* __restrict__ out4) {    // (B, 8) float4 view of (B, 32) floats
  __shared__ vf2 tile[NL][257];
  const int t = threadIdx.x;
  const int p0 = blockIdx.x * 256;

#pragma unroll
  for (int l = 0; l < NL; ++l) {
    tile[l][t] = __builtin_nontemporal_load(ws + (size_t)l * NB + p0 + t);
  }
  __syncthreads();

#pragma unroll
  for (int k = 0; k < 8; ++k) {
    const int q = k * 256 + t;
    const int pq = q >> 3;
    const int wq = q & 7;
    const vf2 a = tile[2 * wq + 0][pq];
    const vf2 c = tile[2 * wq + 1][pq];
    vf4 v; v.x = a.x; v.y = a.y; v.z = c.x; v.w = c.y;
    __builtin_nontemporal_store(v, out4 + (size_t)p0 * 8 + q);
  }
}

// ---- fallback if workspace too small ----
__global__ __launch_bounds__(256) void ngp_fused_kernel(
    const float* __restrict__ x, const float* __restrict__ tables,
    float* __restrict__ out) {
  const int tid = blockIdx.x * blockDim.x + threadIdx.x;
  const int l = tid & (NL - 1);
  const int b = tid >> 4;
  float o0, o1;
  ngp_point_level(x[b * 3], x[b * 3 + 1], x[b * 3 + 2], l, tables, o0, o1);
  float2 r = make_float2(o0, o1);
  ((float2*)out)[tid] = r;
}

extern "C" void kernel_launch(void* const* d_in, const int* in_sizes, int n_in,
                              void* d_out, int out_size, void* d_ws, size_t ws_size,
                              hipStream_t stream) {
  const float* x = (const float*)d_in[0];
  const float* tables = (const float*)d_in[1];
  float* out = (float*)d_out;

  const size_t ws_needed = (size_t)NL * NB * sizeof(vf2);  // 32 MB
  if (ws_size >= ws_needed) {
    vf2* ws = (vf2*)d_ws;
    ngp_gather3<<<GRID_BLOCKS, 512, 0, stream>>>(x, tables, ws);
    ngp_transpose_kernel<<<NB / 256, 256, 0, stream>>>(ws, (vf4*)out);
  } else {
    ngp_fused_kernel<<<NB * NL / 256, 256, 0, stream>>>(x, tables, out);
  }
}